// Round 6
// baseline (203.748 us; speedup 1.0000x reference)
//
#include <hip/hip_runtime.h>
#include <hip/hip_bf16.h>

#define B_ 4
#define S_ 2048
#define D_ 512
#define H_ 8
#define DH_ 64
#define HD_ 512
#define M_ 8192
#define QKVN 1536
#define QKN 1024
#define LOG2E 1.4426950408889634f

typedef __attribute__((ext_vector_type(8))) short bf16x8;
typedef __attribute__((ext_vector_type(4))) float f32x4;
typedef unsigned short u16;

__device__ inline u16 f2bf(float f) {
    __hip_bfloat16 h = __float2bfloat16(f);
    return *reinterpret_cast<u16*>(&h);
}

__device__ inline void async_cp16(const void* g, void* l) {
    __builtin_amdgcn_global_load_lds(
        (const __attribute__((address_space(1))) unsigned int*)g,
        (__attribute__((address_space(3))) unsigned int*)l, 16, 0, 0);
}

// ---------------------------------------------------------------------------
// fp32 -> bf16 cast, 8 elems/thread
// ---------------------------------------------------------------------------
__global__ __launch_bounds__(256) void castbf(const float* __restrict__ src,
                                              u16* __restrict__ dst, int n8)
{
    int i = blockIdx.x * 256 + threadIdx.x;
    if (i < n8) {
        float4 a = *reinterpret_cast<const float4*>(&src[(size_t)i * 8]);
        float4 b = *reinterpret_cast<const float4*>(&src[(size_t)i * 8 + 4]);
        bf16x8 o;
        o[0] = f2bf(a.x); o[1] = f2bf(a.y); o[2] = f2bf(a.z); o[3] = f2bf(a.w);
        o[4] = f2bf(b.x); o[5] = f2bf(b.y); o[6] = f2bf(b.z); o[7] = f2bf(b.w);
        *reinterpret_cast<bf16x8*>(&dst[(size_t)i * 8]) = o;
    }
}

// ---------------------------------------------------------------------------
// Weight prep: z=0,1,2 -> transpose Wq/Wk/Wv (512x512 f32) into WqkvT bf16
// [1536][512]; z=3 -> transpose Wo (512x64) into WoT [64][512].
// ---------------------------------------------------------------------------
__global__ __launch_bounds__(256) void wprep(
    const float* __restrict__ Wq, const float* __restrict__ Wk,
    const float* __restrict__ Wv, const float* __restrict__ Wo,
    u16* __restrict__ WqkvT, u16* __restrict__ WoT)
{
    const int z = blockIdx.z;
    const float* src; u16* dst; int R, C;
    if (z < 3) { src = (z == 0) ? Wq : (z == 1) ? Wk : Wv;
                 dst = WqkvT + (size_t)z * 512 * 512; R = 512; C = 512; }
    else       { if (blockIdx.x) return; src = Wo; dst = WoT; R = 512; C = 64; }

    __shared__ u16 T[64][65];
    const int tid = threadIdx.x;
    const int c0 = blockIdx.x * 64, r0 = blockIdx.y * 64;
#pragma unroll
    for (int i = 0; i < 4; ++i) {
        int idx = i * 256 + tid;
        int r = idx >> 4, q4 = (idx & 15) << 2;
        float4 vv = *reinterpret_cast<const float4*>(&src[(size_t)(r0 + r) * C + c0 + q4]);
        T[r][q4 + 0] = f2bf(vv.x); T[r][q4 + 1] = f2bf(vv.y);
        T[r][q4 + 2] = f2bf(vv.z); T[r][q4 + 3] = f2bf(vv.w);
    }
    __syncthreads();
#pragma unroll
    for (int i = 0; i < 2; ++i) {
        int idx = i * 256 + tid;
        int cc = idx >> 3, jj = idx & 7;
        bf16x8 o;
#pragma unroll
        for (int e = 0; e < 8; ++e) o[e] = (short)T[jj * 8 + e][cc];
        *reinterpret_cast<bf16x8*>(&dst[(size_t)(c0 + cc) * R + r0 + jj * 8]) = o;
    }
}

// ---------------------------------------------------------------------------
// Fused QKV GEMM: [M,512] @ [1536,512]^T. Q/K cols -> qk[M][1024] (q scaled
// by 0.125*log2e); V cols -> vT[B,H,DH,S] directly (packed b64 along s).
// Tile 128x128, BK=64, 4 waves.
// ---------------------------------------------------------------------------
__global__ __launch_bounds__(256) void gemm_qkv(
    const u16* __restrict__ A, const u16* __restrict__ BT,
    const float* __restrict__ bq, const float* __restrict__ bk,
    const float* __restrict__ bv, u16* __restrict__ qk,
    u16* __restrict__ vT, float qscale)
{
    __shared__ __align__(16) u16 As[128 * 64];
    __shared__ __align__(16) u16 Bs[128 * 64];
    const int tid = threadIdx.x, lane = tid & 63, w = tid >> 6;
    const int l15 = lane & 15, l4 = lane >> 4;
    const int tm = blockIdx.y * 128, tn = blockIdx.x * 128;
    const int wm = (w >> 1) * 64, wn = (w & 1) * 64;

    f32x4 acc[4][4] = {};

    for (int k0 = 0; k0 < 512; k0 += 64) {
#pragma unroll
        for (int i = 0; i < 4; ++i) {
            int call = w * 4 + i;
            int c = call * 64 + lane;
            int r = c >> 3, j = c & 7;
            async_cp16(A + (size_t)(tm + r) * 512 + k0 + ((j ^ (r & 7)) << 3),
                       &As[call * 512]);
            async_cp16(BT + (size_t)(tn + r) * 512 + k0 + ((j ^ (r & 7)) << 3),
                       &Bs[call * 512]);
        }
        __syncthreads();
#pragma unroll
        for (int ks = 0; ks < 2; ++ks) {
            bf16x8 af[4], bf[4];
#pragma unroll
            for (int mf = 0; mf < 4; ++mf) {
                int r = wm + mf * 16 + l15;
                int j = ks * 4 + l4;
                af[mf] = *reinterpret_cast<const bf16x8*>(&As[(r * 8 + (j ^ (r & 7))) * 8]);
            }
#pragma unroll
            for (int nf = 0; nf < 4; ++nf) {
                int r = wn + nf * 16 + l15;
                int j = ks * 4 + l4;
                bf[nf] = *reinterpret_cast<const bf16x8*>(&Bs[(r * 8 + (j ^ (r & 7))) * 8]);
            }
#pragma unroll
            for (int mf = 0; mf < 4; ++mf)
#pragma unroll
                for (int nf = 0; nf < 4; ++nf)
                    acc[mf][nf] = __builtin_amdgcn_mfma_f32_16x16x32_bf16(
                        af[mf], bf[nf], acc[mf][nf], 0, 0, 0);
        }
        __syncthreads();
    }
    // epilogue: C/D col=lane&15, row=(lane>>4)*4+reg
#pragma unroll
    for (int nf = 0; nf < 4; ++nf) {
        const int col = tn + wn + nf * 16 + l15;
        if (col < QKN) {
            const float bias_v = (col < 512) ? bq[col] : bk[col - 512];
            const float scl = (col < 512) ? qscale : 1.0f;
#pragma unroll
            for (int mf = 0; mf < 4; ++mf)
#pragma unroll
                for (int r = 0; r < 4; ++r) {
                    int row = tm + wm + mf * 16 + l4 * 4 + r;
                    qk[(size_t)row * QKN + col] = f2bf((acc[mf][nf][r] + bias_v) * scl);
                }
        } else {
            const int dcol = col - QKN;
            const float bias_v = bv[dcol];
            const int hh = dcol >> 6, dd = dcol & 63;
#pragma unroll
            for (int mf = 0; mf < 4; ++mf) {
                int row0 = tm + wm + mf * 16 + l4 * 4;
                int bb = row0 >> 11, s0 = row0 & 2047;
                ushort4 pk;
                pk.x = f2bf(acc[mf][nf][0] + bias_v);
                pk.y = f2bf(acc[mf][nf][1] + bias_v);
                pk.z = f2bf(acc[mf][nf][2] + bias_v);
                pk.w = f2bf(acc[mf][nf][3] + bias_v);
                *reinterpret_cast<ushort4*>(
                    &vT[((size_t)(bb * 8 + hh) * 64 + dd) * S_ + s0]) = pk;
            }
        }
    }
}

// ---------------------------------------------------------------------------
// Flash attention v6 (= round-4 structure + V direct from L2):
// 4 waves x 16 q-rows (64/block), grid 1024 (4 blocks/CU), K tile double-
// buffered in LDS (global_load_lds + chunk-XOR swizzle), V B-fragments
// loaded straight from vT in L2 (XCD swizzle keeps 4 bh x 512KB resident
// per XCD), P bounced through per-wave LDS (b16 writes, 0-conflict swizzle),
// no max-tracking (scores bounded; softmax shift-invariant), l deferred.
// ---------------------------------------------------------------------------
__global__ __launch_bounds__(256) void flash_mfma(
    const u16* __restrict__ qk, const u16* __restrict__ vT,
    const float* __restrict__ pw_ptr, u16* __restrict__ att)
{
    __shared__ __align__(16) u16 Kb[2][4096];   // [64 s][64 d], chunk-swizzled
    __shared__ __align__(16) u16 Ps[4][1024];   // per-wave 16x64 bf16

    const int tid = threadIdx.x, lane = tid & 63, w = tid >> 6;
    const int l15 = lane & 15, l4 = lane >> 4;
    const int bid = blockIdx.x;
    const int x = bid & 7, g = bid >> 3;
    const int bh = x * 4 + (g >> 5), qt = g & 31;
    const int h = bh & 7, b = bh >> 3;
    const float pwl = pw_ptr[0] * LOG2E;

    const u16* qbase = qk + (size_t)b * S_ * QKN + h * 64;
    const u16* kbase = qbase + 512;
    const u16* vtb   = vT + (size_t)bh * DH_ * S_;

    // Q fragments (A: row=lane&15, k=(lane>>4)*8+i); q pre-scaled
    const int sq = qt * 64 + w * 16 + l15;
    bf16x8 qa0 = *reinterpret_cast<const bf16x8*>(&qbase[(size_t)sq * QKN + l4 * 8]);
    bf16x8 qa1 = *reinterpret_cast<const bf16x8*>(&qbase[(size_t)sq * QKN + 32 + l4 * 8]);

    f32x4 accv[4] = {};
    float l_r[4] = {};

#define STAGE(buf, jj) do {                                                        \
    _Pragma("unroll")                                                              \
    for (int i_ = 0; i_ < 2; ++i_) {                                               \
        int call_ = w * 2 + i_;                                                    \
        int c_ = call_ * 64 + lane;                                                \
        int r_ = c_ >> 3, j_ = c_ & 7;                                             \
        async_cp16(kbase + (size_t)((jj) + r_) * QKN + ((j_ ^ (r_ & 7)) << 3),     \
                   &Kb[buf][call_ * 512]);                                         \
    } } while (0)

    STAGE(0, 0);
    __syncthreads();
    int cur = 0;

    for (int t = 0; t < 32; ++t) {
        const int j0 = t << 6;

        // ---- V B-fragments for this tile, direct from L2 (issued early;
        //      consumed after QK^T+softmax => latency hidden) ----
        bf16x8 vb_[4][2];
#pragma unroll
        for (int n = 0; n < 4; ++n)
#pragma unroll
            for (int ks = 0; ks < 2; ++ks)
                vb_[n][ks] = *reinterpret_cast<const bf16x8*>(
                    &vtb[(size_t)(n * 16 + l15) * S_ + j0 + ks * 32 + l4 * 8]);

        if (t < 31) STAGE(cur ^ 1, j0 + 64);

        // ---- QK^T ----
        f32x4 s[4] = {};
        __builtin_amdgcn_s_setprio(1);
#pragma unroll
        for (int c = 0; c < 4; ++c)
#pragma unroll
            for (int ks = 0; ks < 2; ++ks) {
                int rr = c * 16 + l15;
                int j = ks * 4 + l4;
                bf16x8 kb = *reinterpret_cast<const bf16x8*>(
                    &Kb[cur][(rr * 8 + (j ^ (rr & 7))) * 8]);
                s[c] = __builtin_amdgcn_mfma_f32_16x16x32_bf16(
                    (ks == 0) ? qa0 : qa1, kb, s[c], 0, 0, 0);
            }
        __builtin_amdgcn_s_setprio(0);

        // ---- diagonal prior (tile t==qt only; wave-uniform) ----
        if (t == qt) {
#pragma unroll
            for (int c = 0; c < 4; ++c) {
                int col_g = j0 + c * 16 + l15;
#pragma unroll
                for (int r = 0; r < 4; ++r)
                    if (qt * 64 + w * 16 + l4 * 4 + r == col_g) s[c][r] += pwl;
            }
        }

        // ---- P = 2^s, partial sums, P -> per-wave LDS ----
#pragma unroll
        for (int c = 0; c < 4; ++c)
#pragma unroll
            for (int r = 0; r < 4; ++r) {
                float p = exp2f(s[c][r]);
                l_r[r] += p;
                int rr = l4 * 4 + r;
                Ps[w][rr * 64 + ((c * 16 + l15) ^ ((rr & 7) << 3))] = f2bf(p);
            }

        // ---- P fragments (same-wave transpose read) ----
        bf16x8 pa0 = *reinterpret_cast<const bf16x8*>(
            &Ps[w][l15 * 64 + (((0 * 4 + l4) ^ (l15 & 7)) << 3)]);
        bf16x8 pa1 = *reinterpret_cast<const bf16x8*>(
            &Ps[w][l15 * 64 + (((1 * 4 + l4) ^ (l15 & 7)) << 3)]);

        // ---- PV (V from registers) ----
        __builtin_amdgcn_s_setprio(1);
#pragma unroll
        for (int n = 0; n < 4; ++n)
#pragma unroll
            for (int ks = 0; ks < 2; ++ks)
                accv[n] = __builtin_amdgcn_mfma_f32_16x16x32_bf16(
                    (ks == 0) ? pa0 : pa1, vb_[n][ks], accv[n], 0, 0, 0);
        __builtin_amdgcn_s_setprio(0);

        __syncthreads();
        cur ^= 1;
    }
#undef STAGE

    // ---- epilogue ----
#pragma unroll
    for (int r = 0; r < 4; ++r) {
        float tsum = l_r[r];
        tsum += __shfl_xor(tsum, 1); tsum += __shfl_xor(tsum, 2);
        tsum += __shfl_xor(tsum, 4); tsum += __shfl_xor(tsum, 8);
        float inv = 1.0f / tsum;
        int row = qt * 64 + w * 16 + l4 * 4 + r;
#pragma unroll
        for (int n = 0; n < 4; ++n)
            att[(size_t)(b * S_ + row) * HD_ + h * 64 + n * 16 + l15] =
                f2bf(accv[n][r] * inv);
    }
}

// ---------------------------------------------------------------------------
// Output projection: out[M,64] = att[M,512] @ WoT[64,512]^T + bo.
// 1 wave / 16 rows, W fragments direct from L2 (64KB resident). Grid 512.
// ---------------------------------------------------------------------------
__global__ __launch_bounds__(64) void out_proj(
    const u16* __restrict__ att, const u16* __restrict__ WoT,
    const float* __restrict__ bo, float* __restrict__ out)
{
    const int lane = threadIdx.x;
    const int l15 = lane & 15, l4 = lane >> 4;
    const int row0 = blockIdx.x * 16;

    f32x4 acc[4] = {};
#pragma unroll 4
    for (int ks = 0; ks < 16; ++ks) {
        bf16x8 a = *reinterpret_cast<const bf16x8*>(
            &att[(size_t)(row0 + l15) * 512 + ks * 32 + l4 * 8]);
#pragma unroll
        for (int nf = 0; nf < 4; ++nf) {
            bf16x8 bb = *reinterpret_cast<const bf16x8*>(
                &WoT[(size_t)(nf * 16 + l15) * 512 + ks * 32 + l4 * 8]);
            acc[nf] = __builtin_amdgcn_mfma_f32_16x16x32_bf16(a, bb, acc[nf], 0, 0, 0);
        }
    }
#pragma unroll
    for (int nf = 0; nf < 4; ++nf) {
        int n = nf * 16 + l15;
        float bias_v = bo[n];
#pragma unroll
        for (int r = 0; r < 4; ++r)
            out[(size_t)(row0 + l4 * 4 + r) * 64 + n] = acc[nf][r] + bias_v;
    }
}

// ---------------------------------------------------------------------------
extern "C" void kernel_launch(void* const* d_in, const int* in_sizes, int n_in,
                              void* d_out, int out_size, void* d_ws, size_t ws_size,
                              hipStream_t stream)
{
    const float* x  = (const float*)d_in[0];
    const float* Wq = (const float*)d_in[2];
    const float* bq = (const float*)d_in[3];
    const float* Wk = (const float*)d_in[4];
    const float* bk = (const float*)d_in[5];
    const float* Wv = (const float*)d_in[6];
    const float* bv = (const float*)d_in[7];
    const float* Wo = (const float*)d_in[8];
    const float* bo = (const float*)d_in[9];
    const float* pw = (const float*)d_in[10];

    u16* ws = (u16*)d_ws;
    size_t o = 0;
    u16* xb    = ws + o; o += (size_t)M_ * D_;        // 8 MB
    u16* WqkvT = ws + o; o += (size_t)QKVN * D_;      // 1.5 MB
    u16* WoT   = ws + o; o += (size_t)DH_ * HD_;
    u16* qkb   = ws + o; o += (size_t)M_ * QKN;       // 16 MB
    u16* vTt   = ws + o; o += (size_t)M_ * HD_;       // 8 MB
    u16* att   = ws + o; o += (size_t)M_ * HD_;       // 8 MB

    dim3 blk(256);
    castbf<<<dim3(M_ * D_ / 8 / 256), blk, 0, stream>>>(x, xb, M_ * D_ / 8);
    wprep<<<dim3(8, 8, 4), blk, 0, stream>>>(Wq, Wk, Wv, Wo, WqkvT, WoT);

    gemm_qkv<<<dim3(QKVN / 128, M_ / 128), blk, 0, stream>>>(
        xb, WqkvT, bq, bk, bv, qkb, vTt, 0.125f * LOG2E);

    flash_mfma<<<dim3(1024), blk, 0, stream>>>(qkb, vTt, pw, att);

    out_proj<<<dim3(M_ / 16), dim3(64), 0, stream>>>(att, WoT, bo, (float*)d_out);
}

// Round 7
// 127.175 us; speedup vs baseline: 1.6021x; 1.6021x over previous
//
#include <hip/hip_runtime.h>
#include <hip/hip_bf16.h>

#define B_ 4
#define S_ 2048
#define D_ 512
#define H_ 8
#define DH_ 64
#define HD_ 512
#define M_ 8192
#define QKVN 1536
#define QKN 1024
#define LOG2E 1.4426950408889634f

typedef __attribute__((ext_vector_type(8))) short bf16x8;
typedef __attribute__((ext_vector_type(4))) short bf16x4;
typedef __attribute__((ext_vector_type(4))) float f32x4;
typedef unsigned short u16;

__device__ inline u16 f2bf(float f) {
    __hip_bfloat16 h = __float2bfloat16(f);
    return *reinterpret_cast<u16*>(&h);
}

__device__ inline void async_cp16(const void* g, void* l) {
    __builtin_amdgcn_global_load_lds(
        (const __attribute__((address_space(1))) unsigned int*)g,
        (__attribute__((address_space(3))) unsigned int*)l, 16, 0, 0);
}

// 16x16x16 bf16 MFMA (K=16): A/B = 4 bf16 (2 VGPR), C/D = 4 f32.
__device__ inline f32x4 mfma16(bf16x4 a, bf16x4 b, f32x4 c) {
#if __has_builtin(__builtin_amdgcn_mfma_f32_16x16x16bf16_1k)
    return __builtin_amdgcn_mfma_f32_16x16x16bf16_1k(a, b, c, 0, 0, 0);
#else
    asm volatile("v_mfma_f32_16x16x16_bf16 %0, %1, %2, %0"
                 : "+v"(c) : "v"(a), "v"(b));
    return c;
#endif
}

// ---------------------------------------------------------------------------
// fp32 -> bf16 cast, 8 elems/thread
// ---------------------------------------------------------------------------
__global__ __launch_bounds__(256) void castbf(const float* __restrict__ src,
                                              u16* __restrict__ dst, int n8)
{
    int i = blockIdx.x * 256 + threadIdx.x;
    if (i < n8) {
        float4 a = *reinterpret_cast<const float4*>(&src[(size_t)i * 8]);
        float4 b = *reinterpret_cast<const float4*>(&src[(size_t)i * 8 + 4]);
        bf16x8 o;
        o[0] = f2bf(a.x); o[1] = f2bf(a.y); o[2] = f2bf(a.z); o[3] = f2bf(a.w);
        o[4] = f2bf(b.x); o[5] = f2bf(b.y); o[6] = f2bf(b.z); o[7] = f2bf(b.w);
        *reinterpret_cast<bf16x8*>(&dst[(size_t)i * 8]) = o;
    }
}

// ---------------------------------------------------------------------------
// Weight prep: z=0,1,2 -> transpose Wq/Wk/Wv (512x512 f32) into WqkvT bf16
// [1536][512]; z=3 -> transpose Wo (512x64) into WoT [64][512].
// ---------------------------------------------------------------------------
__global__ __launch_bounds__(256) void wprep(
    const float* __restrict__ Wq, const float* __restrict__ Wk,
    const float* __restrict__ Wv, const float* __restrict__ Wo,
    u16* __restrict__ WqkvT, u16* __restrict__ WoT)
{
    const int z = blockIdx.z;
    const float* src; u16* dst; int R, C;
    if (z < 3) { src = (z == 0) ? Wq : (z == 1) ? Wk : Wv;
                 dst = WqkvT + (size_t)z * 512 * 512; R = 512; C = 512; }
    else       { if (blockIdx.x) return; src = Wo; dst = WoT; R = 512; C = 64; }

    __shared__ u16 T[64][65];
    const int tid = threadIdx.x;
    const int c0 = blockIdx.x * 64, r0 = blockIdx.y * 64;
#pragma unroll
    for (int i = 0; i < 4; ++i) {
        int idx = i * 256 + tid;
        int r = idx >> 4, q4 = (idx & 15) << 2;
        float4 vv = *reinterpret_cast<const float4*>(&src[(size_t)(r0 + r) * C + c0 + q4]);
        T[r][q4 + 0] = f2bf(vv.x); T[r][q4 + 1] = f2bf(vv.y);
        T[r][q4 + 2] = f2bf(vv.z); T[r][q4 + 3] = f2bf(vv.w);
    }
    __syncthreads();
#pragma unroll
    for (int i = 0; i < 2; ++i) {
        int idx = i * 256 + tid;
        int cc = idx >> 3, jj = idx & 7;
        bf16x8 o;
#pragma unroll
        for (int e = 0; e < 8; ++e) o[e] = (short)T[jj * 8 + e][cc];
        *reinterpret_cast<bf16x8*>(&dst[(size_t)(c0 + cc) * R + r0 + jj * 8]) = o;
    }
}

// ---------------------------------------------------------------------------
// Fused QKV GEMM: [M,512] @ [1536,512]^T. Q/K cols -> qk[M][1024] (q scaled
// by 0.125*log2e); V cols -> vT[B,H,DH,S] directly (packed b64 along s).
// Tile 128x128, BK=64, 4 waves.
// ---------------------------------------------------------------------------
__global__ __launch_bounds__(256) void gemm_qkv(
    const u16* __restrict__ A, const u16* __restrict__ BT,
    const float* __restrict__ bq, const float* __restrict__ bk,
    const float* __restrict__ bv, u16* __restrict__ qk,
    u16* __restrict__ vT, float qscale)
{
    __shared__ __align__(16) u16 As[128 * 64];
    __shared__ __align__(16) u16 Bs[128 * 64];
    const int tid = threadIdx.x, lane = tid & 63, w = tid >> 6;
    const int l15 = lane & 15, l4 = lane >> 4;
    const int tm = blockIdx.y * 128, tn = blockIdx.x * 128;
    const int wm = (w >> 1) * 64, wn = (w & 1) * 64;

    f32x4 acc[4][4] = {};

    for (int k0 = 0; k0 < 512; k0 += 64) {
#pragma unroll
        for (int i = 0; i < 4; ++i) {
            int call = w * 4 + i;
            int c = call * 64 + lane;
            int r = c >> 3, j = c & 7;
            async_cp16(A + (size_t)(tm + r) * 512 + k0 + ((j ^ (r & 7)) << 3),
                       &As[call * 512]);
            async_cp16(BT + (size_t)(tn + r) * 512 + k0 + ((j ^ (r & 7)) << 3),
                       &Bs[call * 512]);
        }
        __syncthreads();
#pragma unroll
        for (int ks = 0; ks < 2; ++ks) {
            bf16x8 af[4], bf[4];
#pragma unroll
            for (int mf = 0; mf < 4; ++mf) {
                int r = wm + mf * 16 + l15;
                int j = ks * 4 + l4;
                af[mf] = *reinterpret_cast<const bf16x8*>(&As[(r * 8 + (j ^ (r & 7))) * 8]);
            }
#pragma unroll
            for (int nf = 0; nf < 4; ++nf) {
                int r = wn + nf * 16 + l15;
                int j = ks * 4 + l4;
                bf[nf] = *reinterpret_cast<const bf16x8*>(&Bs[(r * 8 + (j ^ (r & 7))) * 8]);
            }
#pragma unroll
            for (int mf = 0; mf < 4; ++mf)
#pragma unroll
                for (int nf = 0; nf < 4; ++nf)
                    acc[mf][nf] = __builtin_amdgcn_mfma_f32_16x16x32_bf16(
                        af[mf], bf[nf], acc[mf][nf], 0, 0, 0);
        }
        __syncthreads();
    }
    // epilogue: C/D col=lane&15, row=(lane>>4)*4+reg
#pragma unroll
    for (int nf = 0; nf < 4; ++nf) {
        const int col = tn + wn + nf * 16 + l15;
        if (col < QKN) {
            const float bias_v = (col < 512) ? bq[col] : bk[col - 512];
            const float scl = (col < 512) ? qscale : 1.0f;
#pragma unroll
            for (int mf = 0; mf < 4; ++mf)
#pragma unroll
                for (int r = 0; r < 4; ++r) {
                    int row = tm + wm + mf * 16 + l4 * 4 + r;
                    qk[(size_t)row * QKN + col] = f2bf((acc[mf][nf][r] + bias_v) * scl);
                }
        } else {
            const int dcol = col - QKN;
            const float bias_v = bv[dcol];
            const int hh = dcol >> 6, dd = dcol & 63;
#pragma unroll
            for (int mf = 0; mf < 4; ++mf) {
                int row0 = tm + wm + mf * 16 + l4 * 4;
                int bb = row0 >> 11, s0 = row0 & 2047;
                ushort4 pk;
                pk.x = f2bf(acc[mf][nf][0] + bias_v);
                pk.y = f2bf(acc[mf][nf][1] + bias_v);
                pk.z = f2bf(acc[mf][nf][2] + bias_v);
                pk.w = f2bf(acc[mf][nf][3] + bias_v);
                *reinterpret_cast<ushort4*>(
                    &vT[((size_t)(bb * 8 + hh) * 64 + dd) * S_ + s0]) = pk;
            }
        }
    }
}

// ---------------------------------------------------------------------------
// Flash attention v7: swapped QK^T + register-resident P via 16x16x16 PV.
// 2 waves x 32 q-rows (64-row block), grid 1024 (4 blocks/CU).
// K tile [64 kv][64 dh] + V tile [64 dh][64 s] double-buffered in LDS
// (global_load_lds, chunk-XOR swizzle — round-4-proven 0-conflict pattern).
// Swapped S^T = mfma(K, Q): lane owns q-row (lane&15), holds kv c*16+l4*4+r
// -> exactly the A-fragment of mfma_16x16x16 (k = l4*4+i), so P feeds PV
// directly from registers: NO P LDS round-trip.
// No max-tracking (scores bounded; softmax shift-invariant), l deferred.
// ---------------------------------------------------------------------------
__global__ __launch_bounds__(128) void flash_mfma(
    const u16* __restrict__ qk, const u16* __restrict__ vT,
    const float* __restrict__ pw_ptr, u16* __restrict__ att)
{
    __shared__ __align__(16) u16 Kb[2][4096];   // [64 kv][64 dh], chunk-swz
    __shared__ __align__(16) u16 Vb[2][4096];   // [64 dh][64 s],  chunk-swz

    const int tid = threadIdx.x, lane = tid & 63, w = tid >> 6;   // w in {0,1}
    const int l15 = lane & 15, l4 = lane >> 4;
    const int bid = blockIdx.x;
    const int x = bid & 7, g = bid >> 3;
    const int bh = x * 4 + (g >> 5), qt = g & 31;
    const int h = bh & 7, b = bh >> 3;
    const float pwl = pw_ptr[0] * LOG2E;

    const u16* qbase = qk + (size_t)b * S_ * QKN + h * 64;
    const u16* kbase = qbase + 512;
    const u16* vtb   = vT + (size_t)bh * DH_ * S_;

    const int qrow0 = qt * 64 + w * 32;   // wave's first q row
    // Q as B-fragments: col = q-row = qrow0+nf*16+l15, k(dh) = ks*32+l4*8+i
    bf16x8 qb[2][2];
#pragma unroll
    for (int nf = 0; nf < 2; ++nf)
#pragma unroll
        for (int ks = 0; ks < 2; ++ks)
            qb[nf][ks] = *reinterpret_cast<const bf16x8*>(
                &qbase[(size_t)(qrow0 + nf * 16 + l15) * QKN + ks * 32 + l4 * 8]);

    f32x4 accv[2][4] = {};
    float l_r[2] = {0.f, 0.f};
    const int diag_t = qt;   // both waves' 32 rows lie inside kv-tile qt

#define STAGE(buf, jj) do {                                                        \
    _Pragma("unroll")                                                              \
    for (int i_ = 0; i_ < 4; ++i_) {                                               \
        int call_ = w * 4 + i_;                                                    \
        int c_ = call_ * 64 + lane;                                                \
        int r_ = c_ >> 3, j_ = c_ & 7;                                             \
        async_cp16(kbase + (size_t)((jj) + r_) * QKN + ((j_ ^ (r_ & 7)) << 3),     \
                   &Kb[buf][call_ * 512]);                                         \
        async_cp16(vtb + (size_t)r_ * S_ + (jj) + ((j_ ^ (r_ & 7)) << 3),          \
                   &Vb[buf][call_ * 512]);                                         \
    } } while (0)

    STAGE(0, 0);
    __syncthreads();
    int cur = 0;

    for (int t = 0; t < 32; ++t) {
        const int j0 = t << 6;
        if (t < 31) STAGE(cur ^ 1, j0 + 64);

        // ---- swapped QK^T: S^T[kv][q], A = K from LDS, B = Q regs ----
        f32x4 s[2][4] = {};
        __builtin_amdgcn_s_setprio(1);
#pragma unroll
        for (int c = 0; c < 4; ++c)
#pragma unroll
            for (int ks = 0; ks < 2; ++ks) {
                const int rr = c * 16 + l15;            // kv row
                const int j = ks * 4 + l4;              // dh chunk
                bf16x8 ka = *reinterpret_cast<const bf16x8*>(
                    &Kb[cur][(rr * 8 + (j ^ (rr & 7))) * 8]);
                s[0][c] = __builtin_amdgcn_mfma_f32_16x16x32_bf16(ka, qb[0][ks], s[0][c], 0, 0, 0);
                s[1][c] = __builtin_amdgcn_mfma_f32_16x16x32_bf16(ka, qb[1][ks], s[1][c], 0, 0, 0);
            }
        __builtin_amdgcn_s_setprio(0);

        // ---- diagonal prior: kv = j0+c*16+l4*4+r, q = qrow0+nf*16+l15 ----
        if (t == diag_t) {
#pragma unroll
            for (int c = 0; c < 4; ++c)
#pragma unroll
                for (int nf = 0; nf < 2; ++nf)
#pragma unroll
                    for (int r = 0; r < 4; ++r)
                        if (j0 + c * 16 + l4 * 4 + r == qrow0 + nf * 16 + l15)
                            s[c][0][0] += 0.f,  // keep shape; real add below
                            s[c - c][0][0] += 0.f;
            // (explicit loop below to avoid mis-indexing)
#pragma unroll
            for (int c = 0; c < 4; ++c)
#pragma unroll
                for (int nf = 0; nf < 2; ++nf)
#pragma unroll
                    for (int r = 0; r < 4; ++r)
                        if (j0 + c * 16 + l4 * 4 + r == qrow0 + nf * 16 + l15)
                            s[nf][c][r] += pwl;
        }

        // ---- P = 2^s in registers (lane-local q-row sums); bf16 pack ----
        bf16x4 p[2][4];
#pragma unroll
        for (int nf = 0; nf < 2; ++nf)
#pragma unroll
            for (int c = 0; c < 4; ++c) {
                float p0 = exp2f(s[nf][c][0]);
                float p1 = exp2f(s[nf][c][1]);
                float p2 = exp2f(s[nf][c][2]);
                float p3 = exp2f(s[nf][c][3]);
                l_r[nf] += (p0 + p1) + (p2 + p3);
                bf16x4 pk;
                pk[0] = (short)f2bf(p0); pk[1] = (short)f2bf(p1);
                pk[2] = (short)f2bf(p2); pk[3] = (short)f2bf(p3);
                p[nf][c] = pk;
            }

        // ---- PV: 16x16x16, A = P regs (row=q=l15, k=kv=l4*4+i),
        //      B = V from LDS (col=dh=l15, k=kv), b64 chunk-swz reads ----
        __builtin_amdgcn_s_setprio(1);
#pragma unroll
        for (int n = 0; n < 4; ++n) {
            const int d = n * 16 + l15;
#pragma unroll
            for (int c = 0; c < 4; ++c) {
                bf16x4 va = *reinterpret_cast<const bf16x4*>(
                    &Vb[cur][d * 64 + 8 * ((c * 2 + (l4 >> 1)) ^ (d & 7)) + (l4 & 1) * 4]);
                accv[0][n] = mfma16(p[0][c], va, accv[0][n]);
                accv[1][n] = mfma16(p[1][c], va, accv[1][n]);
            }
        }
        __builtin_amdgcn_s_setprio(0);

        __syncthreads();
        cur ^= 1;
    }
#undef STAGE

    // ---- epilogue: total l per q-row, then store D (std C/D layout) ----
    float lt[2];
#pragma unroll
    for (int nf = 0; nf < 2; ++nf) {
        float t2 = l_r[nf];
        t2 += __shfl_xor(t2, 16);
        t2 += __shfl_xor(t2, 32);
        lt[nf] = t2;
    }
#pragma unroll
    for (int nf = 0; nf < 2; ++nf)
#pragma unroll
        for (int r = 0; r < 4; ++r) {
            float inv = 1.0f / __shfl(lt[nf], l4 * 4 + r);
            int row = qrow0 + nf * 16 + l4 * 4 + r;
#pragma unroll
            for (int n = 0; n < 4; ++n)
                att[(size_t)(b * S_ + row) * HD_ + h * 64 + n * 16 + l15] =
                    f2bf(accv[nf][n][r] * inv);
        }
}

// ---------------------------------------------------------------------------
// Output projection: out[M,64] = att[M,512] @ WoT[64,512]^T + bo.
// 1 wave / 16 rows, W fragments direct from L2 (64KB resident). Grid 512.
// ---------------------------------------------------------------------------
__global__ __launch_bounds__(64) void out_proj(
    const u16* __restrict__ att, const u16* __restrict__ WoT,
    const float* __restrict__ bo, float* __restrict__ out)
{
    const int lane = threadIdx.x;
    const int l15 = lane & 15, l4 = lane >> 4;
    const int row0 = blockIdx.x * 16;

    f32x4 acc[4] = {};
#pragma unroll 4
    for (int ks = 0; ks < 16; ++ks) {
        bf16x8 a = *reinterpret_cast<const bf16x8*>(
            &att[(size_t)(row0 + l15) * 512 + ks * 32 + l4 * 8]);
#pragma unroll
        for (int nf = 0; nf < 4; ++nf) {
            bf16x8 bb = *reinterpret_cast<const bf16x8*>(
                &WoT[(size_t)(nf * 16 + l15) * 512 + ks * 32 + l4 * 8]);
            acc[nf] = __builtin_amdgcn_mfma_f32_16x16x32_bf16(a, bb, acc[nf], 0, 0, 0);
        }
    }
#pragma unroll
    for (int nf = 0; nf < 4; ++nf) {
        int n = nf * 16 + l15;
        float bias_v = bo[n];
#pragma unroll
        for (int r = 0; r < 4; ++r)
            out[(size_t)(row0 + l4 * 4 + r) * 64 + n] = acc[nf][r] + bias_v;
    }
}

// ---------------------------------------------------------------------------
extern "C" void kernel_launch(void* const* d_in, const int* in_sizes, int n_in,
                              void* d_out, int out_size, void* d_ws, size_t ws_size,
                              hipStream_t stream)
{
    const float* x  = (const float*)d_in[0];
    const float* Wq = (const float*)d_in[2];
    const float* bq = (const float*)d_in[3];
    const float* Wk = (const float*)d_in[4];
    const float* bk = (const float*)d_in[5];
    const float* Wv = (const float*)d_in[6];
    const float* bv = (const float*)d_in[7];
    const float* Wo = (const float*)d_in[8];
    const float* bo = (const float*)d_in[9];
    const float* pw = (const float*)d_in[10];

    u16* ws = (u16*)d_ws;
    size_t o = 0;
    u16* xb    = ws + o; o += (size_t)M_ * D_;        // 8 MB
    u16* WqkvT = ws + o; o += (size_t)QKVN * D_;      // 1.5 MB
    u16* WoT   = ws + o; o += (size_t)DH_ * HD_;
    u16* qkb   = ws + o; o += (size_t)M_ * QKN;       // 16 MB
    u16* vTt   = ws + o; o += (size_t)M_ * HD_;       // 8 MB
    u16* att   = ws + o; o += (size_t)M_ * HD_;       // 8 MB

    dim3 blk(256);
    castbf<<<dim3(M_ * D_ / 8 / 256), blk, 0, stream>>>(x, xb, M_ * D_ / 8);
    wprep<<<dim3(8, 8, 4), blk, 0, stream>>>(Wq, Wk, Wv, Wo, WqkvT, WoT);

    gemm_qkv<<<dim3(QKVN / 128, M_ / 128), blk, 0, stream>>>(
        xb, WqkvT, bq, bk, bv, qkb, vTt, 0.125f * LOG2E);

    flash_mfma<<<dim3(1024), dim3(128), 0, stream>>>(qkb, vTt, pw, att);

    out_proj<<<dim3(M_ / 16), dim3(64), 0, stream>>>(att, WoT, bo, (float*)d_out);
}

// Round 8
// 107.907 us; speedup vs baseline: 1.8882x; 1.1786x over previous
//
#include <hip/hip_runtime.h>
#include <hip/hip_bf16.h>

#define B_ 4
#define S_ 2048
#define D_ 512
#define H_ 8
#define DH_ 64
#define HD_ 512
#define M_ 8192
#define QKVN 1536
#define QKN 1024
#define LOG2E 1.4426950408889634f

typedef __attribute__((ext_vector_type(8))) short bf16x8;
typedef __attribute__((ext_vector_type(4))) float f32x4;
typedef unsigned short u16;

__device__ inline u16 f2bf(float f) {
    __hip_bfloat16 h = __float2bfloat16(f);
    return *reinterpret_cast<u16*>(&h);
}

__device__ inline void async_cp16(const void* g, void* l) {
    __builtin_amdgcn_global_load_lds(
        (const __attribute__((address_space(1))) unsigned int*)g,
        (__attribute__((address_space(3))) unsigned int*)l, 16, 0, 0);
}

// ---------------------------------------------------------------------------
// fp32 -> bf16 cast, 8 elems/thread
// ---------------------------------------------------------------------------
__global__ __launch_bounds__(256) void castbf(const float* __restrict__ src,
                                              u16* __restrict__ dst, int n8)
{
    int i = blockIdx.x * 256 + threadIdx.x;
    if (i < n8) {
        float4 a = *reinterpret_cast<const float4*>(&src[(size_t)i * 8]);
        float4 b = *reinterpret_cast<const float4*>(&src[(size_t)i * 8 + 4]);
        bf16x8 o;
        o[0] = f2bf(a.x); o[1] = f2bf(a.y); o[2] = f2bf(a.z); o[3] = f2bf(a.w);
        o[4] = f2bf(b.x); o[5] = f2bf(b.y); o[6] = f2bf(b.z); o[7] = f2bf(b.w);
        *reinterpret_cast<bf16x8*>(&dst[(size_t)i * 8]) = o;
    }
}

// ---------------------------------------------------------------------------
// Weight prep: z=0,1,2 -> transpose Wq/Wk/Wv (512x512 f32) into WqkvT bf16
// [1536][512]; z=3 -> transpose Wo (512x64) into WoT [64][512].
// ---------------------------------------------------------------------------
__global__ __launch_bounds__(256) void wprep(
    const float* __restrict__ Wq, const float* __restrict__ Wk,
    const float* __restrict__ Wv, const float* __restrict__ Wo,
    u16* __restrict__ WqkvT, u16* __restrict__ WoT)
{
    const int z = blockIdx.z;
    const float* src; u16* dst; int R, C;
    if (z < 3) { src = (z == 0) ? Wq : (z == 1) ? Wk : Wv;
                 dst = WqkvT + (size_t)z * 512 * 512; R = 512; C = 512; }
    else       { if (blockIdx.x) return; src = Wo; dst = WoT; R = 512; C = 64; }

    __shared__ u16 T[64][65];
    const int tid = threadIdx.x;
    const int c0 = blockIdx.x * 64, r0 = blockIdx.y * 64;
#pragma unroll
    for (int i = 0; i < 4; ++i) {
        int idx = i * 256 + tid;
        int r = idx >> 4, q4 = (idx & 15) << 2;
        float4 vv = *reinterpret_cast<const float4*>(&src[(size_t)(r0 + r) * C + c0 + q4]);
        T[r][q4 + 0] = f2bf(vv.x); T[r][q4 + 1] = f2bf(vv.y);
        T[r][q4 + 2] = f2bf(vv.z); T[r][q4 + 3] = f2bf(vv.w);
    }
    __syncthreads();
#pragma unroll
    for (int i = 0; i < 2; ++i) {
        int idx = i * 256 + tid;
        int cc = idx >> 3, jj = idx & 7;
        bf16x8 o;
#pragma unroll
        for (int e = 0; e < 8; ++e) o[e] = (short)T[jj * 8 + e][cc];
        *reinterpret_cast<bf16x8*>(&dst[(size_t)(c0 + cc) * R + r0 + jj * 8]) = o;
    }
}

// ---------------------------------------------------------------------------
// Fused QKV GEMM: [M,512] @ [1536,512]^T. Q/K cols -> qk[M][1024] (q scaled
// by 0.125*log2e); V cols -> vT[B,H,DH,S] directly (packed b64 along s).
// Tile 128x128, BK=64, 4 waves.
// ---------------------------------------------------------------------------
__global__ __launch_bounds__(256) void gemm_qkv(
    const u16* __restrict__ A, const u16* __restrict__ BT,
    const float* __restrict__ bq, const float* __restrict__ bk,
    const float* __restrict__ bv, u16* __restrict__ qk,
    u16* __restrict__ vT, float qscale)
{
    __shared__ __align__(16) u16 As[128 * 64];
    __shared__ __align__(16) u16 Bs[128 * 64];
    const int tid = threadIdx.x, lane = tid & 63, w = tid >> 6;
    const int l15 = lane & 15, l4 = lane >> 4;
    const int tm = blockIdx.y * 128, tn = blockIdx.x * 128;
    const int wm = (w >> 1) * 64, wn = (w & 1) * 64;

    f32x4 acc[4][4] = {};

    for (int k0 = 0; k0 < 512; k0 += 64) {
#pragma unroll
        for (int i = 0; i < 4; ++i) {
            int call = w * 4 + i;
            int c = call * 64 + lane;
            int r = c >> 3, j = c & 7;
            async_cp16(A + (size_t)(tm + r) * 512 + k0 + ((j ^ (r & 7)) << 3),
                       &As[call * 512]);
            async_cp16(BT + (size_t)(tn + r) * 512 + k0 + ((j ^ (r & 7)) << 3),
                       &Bs[call * 512]);
        }
        __syncthreads();
#pragma unroll
        for (int ks = 0; ks < 2; ++ks) {
            bf16x8 af[4], bf[4];
#pragma unroll
            for (int mf = 0; mf < 4; ++mf) {
                int r = wm + mf * 16 + l15;
                int j = ks * 4 + l4;
                af[mf] = *reinterpret_cast<const bf16x8*>(&As[(r * 8 + (j ^ (r & 7))) * 8]);
            }
#pragma unroll
            for (int nf = 0; nf < 4; ++nf) {
                int r = wn + nf * 16 + l15;
                int j = ks * 4 + l4;
                bf[nf] = *reinterpret_cast<const bf16x8*>(&Bs[(r * 8 + (j ^ (r & 7))) * 8]);
            }
#pragma unroll
            for (int mf = 0; mf < 4; ++mf)
#pragma unroll
                for (int nf = 0; nf < 4; ++nf)
                    acc[mf][nf] = __builtin_amdgcn_mfma_f32_16x16x32_bf16(
                        af[mf], bf[nf], acc[mf][nf], 0, 0, 0);
        }
        __syncthreads();
    }
    // epilogue: C/D col=lane&15, row=(lane>>4)*4+reg
#pragma unroll
    for (int nf = 0; nf < 4; ++nf) {
        const int col = tn + wn + nf * 16 + l15;
        if (col < QKN) {
            const float bias_v = (col < 512) ? bq[col] : bk[col - 512];
            const float scl = (col < 512) ? qscale : 1.0f;
#pragma unroll
            for (int mf = 0; mf < 4; ++mf)
#pragma unroll
                for (int r = 0; r < 4; ++r) {
                    int row = tm + wm + mf * 16 + l4 * 4 + r;
                    qk[(size_t)row * QKN + col] = f2bf((acc[mf][nf][r] + bias_v) * scl);
                }
        } else {
            const int dcol = col - QKN;
            const float bias_v = bv[dcol];
            const int hh = dcol >> 6, dd = dcol & 63;
#pragma unroll
            for (int mf = 0; mf < 4; ++mf) {
                int row0 = tm + wm + mf * 16 + l4 * 4;
                int bb = row0 >> 11, s0 = row0 & 2047;
                ushort4 pk;
                pk.x = f2bf(acc[mf][nf][0] + bias_v);
                pk.y = f2bf(acc[mf][nf][1] + bias_v);
                pk.z = f2bf(acc[mf][nf][2] + bias_v);
                pk.w = f2bf(acc[mf][nf][3] + bias_v);
                *reinterpret_cast<ushort4*>(
                    &vT[((size_t)(bb * 8 + hh) * 64 + dd) * S_ + s0]) = pk;
            }
        }
    }
}

// ---------------------------------------------------------------------------
// Flash attention v8: swapped QK^T + pi-permuted K staging => P is produced
// directly in the 16x16x32 PV A-fragment layout. Zero P LDS traffic, zero
// cross-lane exchange, full-rate K=32 MFMA throughout.
//   pi(rho): rho=[c1 c0 | l1 l0 | r1 r0] -> kv=[c1 | l1 l0 | c0 | r1 r0]
//   S^T subtile c, lane(l15,l4), reg r  ->  kv = (c>>1)*32 + l4*8 + (c&1)*4 + r
//   which IS A-frag k = l4*8 + i (i=(c&1)*4+r) of the ks=(c>>1) PV window.
// 4 waves x 16 q-rows (64-row block), grid 1024 (4 blocks/CU, 16 waves/CU).
// K tile [64][64] (pi-permuted rows) + V tile [64 d][64 kv], both double-
// buffered, chunk-XOR swizzled (round-4-proven 0-conflict b128 patterns).
// No max-tracking (scores bounded; softmax shift-invariant), l deferred.
// ---------------------------------------------------------------------------
__global__ __launch_bounds__(256, 4) void flash_mfma(
    const u16* __restrict__ qk, const u16* __restrict__ vT,
    const float* __restrict__ pw_ptr, u16* __restrict__ att)
{
    __shared__ __align__(16) u16 Kb[2][4096];   // [64 rho][64 dh], chunk-swz
    __shared__ __align__(16) u16 Vb[2][4096];   // [64 d][64 kv],  chunk-swz

    const int tid = threadIdx.x, lane = tid & 63, w = tid >> 6;
    const int l15 = lane & 15, l4 = lane >> 4;
    const int bid = blockIdx.x;
    const int x = bid & 7, g = bid >> 3;
    const int bh = x * 4 + (g >> 5), qt = g & 31;
    const int h = bh & 7, b = bh >> 3;
    const float pwl = pw_ptr[0] * LOG2E;

    const u16* qbase = qk + (size_t)b * S_ * QKN + h * 64;
    const u16* kbase = qbase + 512;
    const u16* vtb   = vT + (size_t)bh * DH_ * S_;

    const int qrow0 = qt * 64 + w * 16;   // wave's first q row
    // Q as B-fragments: col = q-row = qrow0 + l15, k(dh) = ks2*32 + l4*8 + i
    bf16x8 qb[2];
#pragma unroll
    for (int ks2 = 0; ks2 < 2; ++ks2)
        qb[ks2] = *reinterpret_cast<const bf16x8*>(
            &qbase[(size_t)(qrow0 + l15) * QKN + ks2 * 32 + l4 * 8]);

    f32x4 accv[4] = {};
    float l_r = 0.f;
    const int diag_t = qt;

    // Stage: K rows pi-permuted; V rows linear (d). Dest always linear.
#define STAGE(buf, jj) do {                                                        \
    _Pragma("unroll")                                                              \
    for (int i_ = 0; i_ < 2; ++i_) {                                               \
        int call_ = w * 2 + i_;                                                    \
        int c_ = call_ * 64 + lane;                                                \
        int rho_ = c_ >> 3, j_ = c_ & 7;                                           \
        int pi_ = (rho_ & 32) | ((rho_ & 12) << 1) | ((rho_ & 16) >> 2)            \
                | (rho_ & 3);                                                      \
        async_cp16(kbase + (size_t)((jj) + pi_) * QKN + ((j_ ^ (rho_ & 7)) << 3),  \
                   &Kb[buf][call_ * 512]);                                         \
        async_cp16(vtb + (size_t)rho_ * S_ + (jj) + ((j_ ^ (rho_ & 7)) << 3),      \
                   &Vb[buf][call_ * 512]);                                         \
    } } while (0)

    STAGE(0, 0);
    __syncthreads();
    int cur = 0;

    for (int t = 0; t < 32; ++t) {
        const int j0 = t << 6;
        if (t < 31) STAGE(cur ^ 1, j0 + 64);

        // ---- swapped QK^T: S^T[rho][q], A = K(permuted) LDS, B = Q regs ----
        f32x4 s[4] = {};
        __builtin_amdgcn_s_setprio(1);
#pragma unroll
        for (int c = 0; c < 4; ++c)
#pragma unroll
            for (int ks2 = 0; ks2 < 2; ++ks2) {
                const int rr = c * 16 + l15;           // rho row
                const int sl = ks2 * 4 + l4;           // dh 16B-slot
                bf16x8 ka = *reinterpret_cast<const bf16x8*>(
                    &Kb[cur][(rr * 8 + (sl ^ (rr & 7))) * 8]);
                s[c] = __builtin_amdgcn_mfma_f32_16x16x32_bf16(ka, qb[ks2], s[c], 0, 0, 0);
            }
        __builtin_amdgcn_s_setprio(0);

        // ---- diagonal prior: kv = (c>>1)*32 + l4*8 + (c&1)*4 + r ----
        if (t == diag_t) {
#pragma unroll
            for (int c = 0; c < 4; ++c)
#pragma unroll
                for (int r = 0; r < 4; ++r) {
                    int kv = (c >> 1) * 32 + l4 * 8 + (c & 1) * 4 + r;
                    if (j0 + kv == qrow0 + l15) s[c][r] += pwl;
                }
        }

        // ---- P = 2^s -> PV A-fragments (pure registers) ----
        bf16x8 pa[2];
#pragma unroll
        for (int ks = 0; ks < 2; ++ks)
#pragma unroll
            for (int d2 = 0; d2 < 2; ++d2)
#pragma unroll
                for (int r = 0; r < 4; ++r) {
                    float p = exp2f(s[ks * 2 + d2][r]);
                    l_r += p;
                    pa[ks][d2 * 4 + r] = (short)f2bf(p);
                }

        // ---- PV: 16x16x32, A = P regs, B = V from LDS (b128, swz) ----
        __builtin_amdgcn_s_setprio(1);
#pragma unroll
        for (int nf = 0; nf < 4; ++nf) {
            const int d = nf * 16 + l15;
#pragma unroll
            for (int ks = 0; ks < 2; ++ks) {
                const int sl = ks * 4 + l4;
                bf16x8 vb = *reinterpret_cast<const bf16x8*>(
                    &Vb[cur][(d * 8 + (sl ^ (d & 7))) * 8]);
                accv[nf] = __builtin_amdgcn_mfma_f32_16x16x32_bf16(pa[ks], vb, accv[nf], 0, 0, 0);
            }
        }
        __builtin_amdgcn_s_setprio(0);

        __syncthreads();
        cur ^= 1;
    }
#undef STAGE

    // ---- epilogue: l total per q-row (q = l15 lanes hold partials) ----
    float lt = l_r;
    lt += __shfl_xor(lt, 16);
    lt += __shfl_xor(lt, 32);
    // D rows: q = l4*4 + r; that q's l lives in lanes with l15 == l4*4+r
#pragma unroll
    for (int r = 0; r < 4; ++r) {
        float inv = 1.0f / __shfl(lt, l4 * 4 + r);
        int row = qrow0 + l4 * 4 + r;
#pragma unroll
        for (int nf = 0; nf < 4; ++nf)
            att[(size_t)(b * S_ + row) * HD_ + h * 64 + nf * 16 + l15] =
                f2bf(accv[nf][r] * inv);
    }
}

// ---------------------------------------------------------------------------
// Output projection: out[M,64] = att[M,512] @ WoT[64,512]^T + bo.
// 1 wave / 16 rows, W fragments direct from L2 (64KB resident). Grid 512.
// ---------------------------------------------------------------------------
__global__ __launch_bounds__(64) void out_proj(
    const u16* __restrict__ att, const u16* __restrict__ WoT,
    const float* __restrict__ bo, float* __restrict__ out)
{
    const int lane = threadIdx.x;
    const int l15 = lane & 15, l4 = lane >> 4;
    const int row0 = blockIdx.x * 16;

    f32x4 acc[4] = {};
#pragma unroll 4
    for (int ks = 0; ks < 16; ++ks) {
        bf16x8 a = *reinterpret_cast<const bf16x8*>(
            &att[(size_t)(row0 + l15) * 512 + ks * 32 + l4 * 8]);
#pragma unroll
        for (int nf = 0; nf < 4; ++nf) {
            bf16x8 bb = *reinterpret_cast<const bf16x8*>(
                &WoT[(size_t)(nf * 16 + l15) * 512 + ks * 32 + l4 * 8]);
            acc[nf] = __builtin_amdgcn_mfma_f32_16x16x32_bf16(a, bb, acc[nf], 0, 0, 0);
        }
    }
#pragma unroll
    for (int nf = 0; nf < 4; ++nf) {
        int n = nf * 16 + l15;
        float bias_v = bo[n];
#pragma unroll
        for (int r = 0; r < 4; ++r)
            out[(size_t)(row0 + l4 * 4 + r) * 64 + n] = acc[nf][r] + bias_v;
    }
}

// ---------------------------------------------------------------------------
extern "C" void kernel_launch(void* const* d_in, const int* in_sizes, int n_in,
                              void* d_out, int out_size, void* d_ws, size_t ws_size,
                              hipStream_t stream)
{
    const float* x  = (const float*)d_in[0];
    const float* Wq = (const float*)d_in[2];
    const float* bq = (const float*)d_in[3];
    const float* Wk = (const float*)d_in[4];
    const float* bk = (const float*)d_in[5];
    const float* Wv = (const float*)d_in[6];
    const float* bv = (const float*)d_in[7];
    const float* Wo = (const float*)d_in[8];
    const float* bo = (const float*)d_in[9];
    const float* pw = (const float*)d_in[10];

    u16* ws = (u16*)d_ws;
    size_t o = 0;
    u16* xb    = ws + o; o += (size_t)M_ * D_;        // 8 MB
    u16* WqkvT = ws + o; o += (size_t)QKVN * D_;      // 1.5 MB
    u16* WoT   = ws + o; o += (size_t)DH_ * HD_;
    u16* qkb   = ws + o; o += (size_t)M_ * QKN;       // 16 MB
    u16* vTt   = ws + o; o += (size_t)M_ * HD_;       // 8 MB
    u16* att   = ws + o; o += (size_t)M_ * HD_;       // 8 MB

    dim3 blk(256);
    castbf<<<dim3(M_ * D_ / 8 / 256), blk, 0, stream>>>(x, xb, M_ * D_ / 8);
    wprep<<<dim3(8, 8, 4), blk, 0, stream>>>(Wq, Wk, Wv, Wo, WqkvT, WoT);

    gemm_qkv<<<dim3(QKVN / 128, M_ / 128), blk, 0, stream>>>(
        xb, WqkvT, bq, bk, bv, qkb, vTt, 0.125f * LOG2E);

    flash_mfma<<<dim3(1024), blk, 0, stream>>>(qkb, vTt, pw, att);

    out_proj<<<dim3(M_ / 16), dim3(64), 0, stream>>>(att, WoT, bo, (float*)d_out);
}